// Round 24
// baseline (93.742 us; speedup 1.0000x reference)
//
#include <hip/hip_runtime.h>
#include <hip/hip_fp8.h>

typedef unsigned int uint;
typedef unsigned char uchar;
using f32x4 = __attribute__((ext_vector_type(4))) float;

#define NHALF 2048
#define DIM   1024
#define MROWS 4096
#define KMED  8388607u
#define NTRI  528            // 32*33/2 lower-triangle 128x128 blocks

// workspace layout (bytes) — fp8 panels, no L2 matrix
#define AH_OFF   0ull                          // 4 MB fp8 e4m3
#define SQ_OFF   4194304ull                    // 16 KB f32 sq norms (exact)
#define GHT_OFF  (SQ_OFF + 16384ull)           // 65600 B: TOTAL hist bits 29:16 (16384 u32) + low word [16384]
#define GHN_OFF  (GHT_OFF + 65600ull)          // 65600 B: NEG (cross-half) hist + low word
#define CNT_OFF  (GHN_OFF + 65600ull)          // 16 B: cnt[0]=flush-done
#define ZERO_WORDS 32804                       // (65600*2 + 16)/4 from GHT_OFF

#define AGLOAD(p) __hip_atomic_load((p), __ATOMIC_RELAXED, __HIP_MEMORY_SCOPE_AGENT)

// ---------------------------------------------------------------- dispatch 1: zero scratch + f32->fp8 + sqnorm
__global__ __launch_bounds__(256) void convert_kernel(const float* __restrict__ src,
                                                      const float* __restrict__ tgt,
                                                      char* __restrict__ wsb) {
    uchar* ah = (uchar*)(wsb + AH_OFF);
    float* sq = (float*)(wsb + SQ_OFF);
    uint*  z  = (uint*)(wsb + GHT_OFF);
    int t = threadIdx.x, row = blockIdx.x;
    int g = row * 256 + t;
    if (g < ZERO_WORDS) z[g] = 0;              // zeros both hists + counters
    const float* p = (row < NHALF) ? src + (size_t)row * DIM
                                   : tgt + (size_t)(row - NHALF) * DIM;
    float4 v = reinterpret_cast<const float4*>(p)[t];
    float s = v.x * v.x + v.y * v.y + v.z * v.z + v.w * v.w;
    uchar4 u4;
    u4.x = __hip_fp8_e4m3(v.x).__x;
    u4.y = __hip_fp8_e4m3(v.y).__x;
    u4.z = __hip_fp8_e4m3(v.z).__x;
    u4.w = __hip_fp8_e4m3(v.w).__x;
    reinterpret_cast<uchar4*>(ah + (size_t)row * DIM)[t] = u4;
    for (int o = 32; o; o >>= 1) s += __shfl_down(s, o);
    __shared__ float red[4];
    if ((t & 63) == 0) red[t >> 6] = s;
    __syncthreads();
    if (t == 0) sq[row] = red[0] + red[1] + red[2] + red[3];
}

// ---------------------------------------------------------------- dispatch 2: fp8 GEMM + hist + last-block {median, hist-loss}
// stage 1 KB chunk cidx (32 rows x 32 B) of [buf][arr]; wave-uniform LDS base + lane*16
#define STAGE8(buf, arr, rb, cidx) do {                                                    \
    int _row = (cidx) * 32 + (lane >> 1);                                                  \
    const uchar* _g = ah + ((size_t)((rb) + _row) * DIM + kk0 + (lane & 1) * 16);          \
    __builtin_amdgcn_global_load_lds(                                                      \
        (const __attribute__((address_space(1))) uint*)_g,                                 \
        (__attribute__((address_space(3))) uint*)(&lds[buf][arr][0][0] + (size_t)(cidx) * 1024), \
        16, 0, 0);                                                                         \
} while (0)

__global__ __launch_bounds__(512, 4) void gemm_kernel(char* __restrict__ wsb,
                                                      float* __restrict__ out) {
    const uchar* ah = (const uchar*)(wsb + AH_OFF);
    const float* sq = (const float*)(wsb + SQ_OFF);
    uint*  ght = (uint*)(wsb + GHT_OFF);
    uint*  ghn = (uint*)(wsb + GHN_OFF);
    uint*  cnt = (uint*)(wsb + CNT_OFF);

    // union: fp8 staging [2buf][2arr][128][32] (16 KB) / hist (32 KB)
    __shared__ __align__(16) uint shmem[8192];
    __shared__ uint lowcnt;
    __shared__ float fred[8];
    uchar (*lds)[2][128][32] = (uchar (*)[2][128][32])shmem;

    // XCD swizzle (528 = 8*66, bijective) then triangular decode
    int b = (int)blockIdx.x;
    b = (b & 7) * 66 + (b >> 3);
    int bi = (int)((sqrtf(8.0f * (float)b + 1.0f) - 1.0f) * 0.5f);
    while ((bi + 1) * (bi + 2) / 2 <= b) ++bi;
    while (bi * (bi + 1) / 2 > b) --bi;
    int bj = b - bi * (bi + 1) / 2;          // bj <= bi

    int t = threadIdx.x;
    int lane = t & 63, wid = t >> 6;         // 8 waves
    int wm = wid >> 2, wn = wid & 3;         // 2x4 wave grid: 64 rows x 32 cols per wave
    int rowbase = bi * 128, colbase = bj * 128;

    f32x4 acc[4][2] = {};
    int fr = lane & 15;
    int fk8 = (lane >> 4) * 8;               // byte offset of this lane's 8 K-elements

    int sarr = wid >> 2, scid = wid & 3;     // staging role: wave -> {array, chunk}
    int srb  = sarr ? colbase : rowbase;

    {   // prologue: stage k-step 0 into buffer 0 (each wave: 1 chunk)
        int kk0 = 0;
        STAGE8(0, sarr, srb, scid);
    }
    __syncthreads();

    int cur = 0;
    for (int kt = 0; kt < 32; ++kt) {
        if (kt < 31) {                        // issue next-tile loads BEFORE compute
            int kk0 = (kt + 1) * 32;
            int nb = cur ^ 1;
            STAGE8(nb, sarr, srb, scid);
        }
        long fa[4], fb[2];
#pragma unroll
        for (int m = 0; m < 4; ++m)
            fa[m] = *reinterpret_cast<const long*>(&lds[cur][0][wm * 64 + m * 16 + fr][fk8]);
#pragma unroll
        for (int n = 0; n < 2; ++n)
            fb[n] = *reinterpret_cast<const long*>(&lds[cur][1][wn * 32 + n * 16 + fr][fk8]);
#pragma unroll
        for (int m = 0; m < 4; ++m)
#pragma unroll
            for (int n = 0; n < 2; ++n)
                acc[m][n] = __builtin_amdgcn_mfma_f32_16x16x32_fp8_fp8(fa[m], fb[n], acc[m][n], 0, 0, 0);
        __syncthreads();                      // drains next-tile vmcnt + this tile's readers
        cur ^= 1;
    }

    // ---- phase 2: bit30-split hist from registers (sign is BLOCK-uniform)
    uint* h = shmem;                          // 8192 packed words = 32 KB
    for (int i = t; i < 8192; i += 512) h[i] = 0;
    if (t == 0) lowcnt = 0;
    __syncthreads();

    uint w = (bi == bj) ? 1u : 2u;
    int fq = lane >> 4;
#pragma unroll
    for (int m = 0; m < 4; ++m) {
#pragma unroll
        for (int n = 0; n < 2; ++n) {
            int gj = colbase + wn * 32 + n * 16 + fr;
            float sqj = sq[gj];
#pragma unroll
            for (int r = 0; r < 4; ++r) {
                int gi = rowbase + wm * 64 + m * 16 + fq * 4 + r;
                float v = fmaxf(sq[gi] + sqj - 2.0f * acc[m][n][r], 0.0f);
                uint bits = __float_as_uint(v);
                if (bits & 0x40000000u) {
                    uint k14 = (bits >> 16) & 0x3FFFu;
                    atomicAdd(&h[k14 >> 1], (k14 & 1) ? (w << 16) : w);
                } else {
                    atomicAdd(&lowcnt, w);             // rare (diag zeros + tiny tail)
                }
            }
        }
    }
    __syncthreads();

    // ---- phase 3: flush. Always -> total; cross-half blocks also -> neg hist.
    bool crosshalf = (bi < 16) != (bj < 16);
    for (int i = t; i < 8192; i += 512) {
        uint wd = h[i];
        if (wd) {
            uint lo = wd & 0xFFFFu, hi2 = wd >> 16;
            if (lo)  { atomicAdd(&ght[2 * i],     lo);  if (crosshalf) atomicAdd(&ghn[2 * i],     lo); }
            if (hi2) { atomicAdd(&ght[2 * i + 1], hi2); if (crosshalf) atomicAdd(&ghn[2 * i + 1], hi2); }
        }
    }
    if (t == 0 && lowcnt) {
        atomicAdd(&ght[16384], lowcnt);
        if (crosshalf) atomicAdd(&ghn[16384], lowcnt);
    }

    // ---- phase 4: last-flusher computes median AND loss from the histograms
    __syncthreads();
    if (t == 0) {
        __threadfence();
        h[0] = (atomicAdd(&cnt[0], 1u) == gridDim.x - 1) ? 1u : 0u;
    }
    __syncthreads();
    bool last = h[0] != 0;
    __syncthreads();
    if (!last) return;

    uint* part = h + 16;       // 512
    uint* loc  = h + 544;      // 2
    uint* lin  = h + 560;      // 32
    uint s = 0;
    for (int i = 0; i < 32; ++i) s += AGLOAD(&ght[t * 32 + i]);   // 512 thr x 32 bins
    part[t] = s;
    __syncthreads();
    if (t == 0) {
        uint k = KMED - AGLOAD(&ght[16384]);   // below-2.0 values rank below everything
        uint cum = 0; int seg = 0;
        for (; seg < 512; ++seg) { uint c = part[seg]; if (cum + c > k) break; cum += c; }
        loc[0] = (uint)seg; loc[1] = k - cum;
    }
    __syncthreads();
    int seg = (int)loc[0];
    if (t < 32) lin[t] = AGLOAD(&ght[seg * 32 + t]);
    __syncthreads();
    if (t == 0) {
        uint k = loc[1], cum = 0; int bb = 0;
        for (; bb < 32; ++bb) { uint c = lin[bb]; if (cum + c > k) break; cum += c; }
        // median resolved to bits >= 16; bin midpoint (err <= 8 abs @ ~2048)
        uint mbits = 0x40000000u | ((uint)(seg * 32 + bb) << 16) | 0x8000u;
        float median = __uint_as_float(mbits);
        float logn = logf(2048.0f + 1e-8f);
        float bw = sqrtf(0.5f * median / logn);
        out[1] = bw;                               // bandwidth
        ((float*)loc)[1] = logn / median;          // itb -> LDS for all threads
    }
    __syncthreads();
    float itb = ((float*)loc)[1];

    // loss = sum over bins of (total - 2*neg) * exp(-mid * itb), + low-count at exp(0)=1
    float local = 0.0f;
    for (int i = 0; i < 32; ++i) {
        int bidx = t * 32 + i;
        int tot = (int)AGLOAD(&ght[bidx]);
        int neg = (int)AGLOAD(&ghn[bidx]);
        int sgn = tot - 2 * neg;
        if (sgn) {
            float mid = __uint_as_float(0x40000000u | ((uint)bidx << 16) | 0x8000u);
            local += (float)sgn * __expf(-mid * itb);
        }
    }
    if (t == 0)
        local += (float)((int)AGLOAD(&ght[16384]) - 2 * (int)AGLOAD(&ghn[16384]));  // exp(0)=1
    for (int o = 32; o; o >>= 1) local += __shfl_down(local, o);
    if ((t & 63) == 0) fred[t >> 6] = local;
    __syncthreads();
    if (t == 0) {
        float bs = fred[0] + fred[1] + fred[2] + fred[3]
                 + fred[4] + fred[5] + fred[6] + fred[7];
        out[0] = bs / 4194304.0f;              // mean over N*N, N=2048
    }
}

// ---------------------------------------------------------------- launch (2 dispatches)
extern "C" void kernel_launch(void* const* d_in, const int* in_sizes, int n_in,
                              void* d_out, int out_size, void* d_ws, size_t ws_size,
                              hipStream_t stream) {
    const float* src = (const float*)d_in[0];
    const float* tgt = (const float*)d_in[1];
    float* out = (float*)d_out;
    char* ws = (char*)d_ws;

    convert_kernel<<<MROWS, 256, 0, stream>>>(src, tgt, ws);
    gemm_kernel<<<NTRI, 512, 0, stream>>>(ws, out);
}

// Round 25
// 83.415 us; speedup vs baseline: 1.1238x; 1.1238x over previous
//
#include <hip/hip_runtime.h>

typedef unsigned int uint;
typedef unsigned short ushort;
using short8 = __attribute__((ext_vector_type(8))) short;   // 8 bf16 (4 VGPRs)
using f32x4  = __attribute__((ext_vector_type(4))) float;

#define NHALF 2048
#define DIM   1024
#define MROWS 4096
#define KMED  8388607u
#define NTRI  136            // 16*17/2 lower-triangle 256x256 blocks

// workspace layout (bytes) — no L2 matrix
#define AH_OFF   0ull                          // 8 MB bf16
#define SQ_OFF   8388608ull                    // 16 KB f32 sq norms (exact)
#define GHT_OFF  (SQ_OFF + 16384ull)           // 65600 B: TOTAL hist bits 29:16 + low word [16384]
#define GHN_OFF  (GHT_OFF + 65600ull)          // 65600 B: NEG (cross-half) hist + low word
#define CNT_OFF  (GHN_OFF + 65600ull)          // 16 B: cnt[0]=flush-done
#define ZERO_WORDS 32804                       // (65600*2 + 16)/4 from GHT_OFF

#define AGLOAD(p) __hip_atomic_load((p), __ATOMIC_RELAXED, __HIP_MEMORY_SCOPE_AGENT)

__device__ __forceinline__ ushort f2bf(float x) {
    uint u = __float_as_uint(x);
    u += 0x7FFFu + ((u >> 16) & 1u);           // RNE
    return (ushort)(u >> 16);
}

// ---------------------------------------------------------------- dispatch 1: zero scratch + f32->bf16 + sqnorm
__global__ __launch_bounds__(256) void convert_kernel(const float* __restrict__ src,
                                                      const float* __restrict__ tgt,
                                                      char* __restrict__ wsb) {
    ushort* ah = (ushort*)(wsb + AH_OFF);
    float*  sq = (float*)(wsb + SQ_OFF);
    uint*   z  = (uint*)(wsb + GHT_OFF);
    int t = threadIdx.x, row = blockIdx.x;
    int g = row * 256 + t;
    if (g < ZERO_WORDS) z[g] = 0;              // zeros both hists + counters
    const float* p = (row < NHALF) ? src + (size_t)row * DIM
                                   : tgt + (size_t)(row - NHALF) * DIM;
    float4 v = reinterpret_cast<const float4*>(p)[t];
    float xs[4] = {v.x, v.y, v.z, v.w};
    ushort hh[4];
    float s = 0.0f;
#pragma unroll
    for (int e = 0; e < 4; ++e) { float x = xs[e]; s += x * x; hh[e] = f2bf(x); }
    ushort4 h4; h4.x = hh[0]; h4.y = hh[1]; h4.z = hh[2]; h4.w = hh[3];
    reinterpret_cast<ushort4*>(ah + (size_t)row * DIM)[t] = h4;
    for (int o = 32; o; o >>= 1) s += __shfl_down(s, o);
    __shared__ float red[4];
    if ((t & 63) == 0) red[t >> 6] = s;
    __syncthreads();
    if (t == 0) sq[row] = red[0] + red[1] + red[2] + red[3];
}

// ---------------------------------------------------------------- dispatch 2: 8-phase 256x256 GEMM + hist + median/loss tail
// stage unit u of k-tile kt into buffer buf.  u: 0=A rows[0,128) 1=A[128,256) 2=B[0,128) 3=B[128,256)
// Each wave issues 2 global_load_lds (1 KB each).  LDS dest linear; global source pre-swizzled:
// LDS row R physical 16B-chunk P holds global chunk P ^ (R&7)  (chunk-XOR, both-sides rule).
#define STAGEU(buf, u, kt) do {                                                            \
    int _arr = (u) >> 1;                                                                   \
    int _rb  = _arr ? colbase : rowbase;                                                   \
    _Pragma("unroll")                                                                      \
    for (int _l = 0; _l < 2; ++_l) {                                                       \
        int _r0 = ((u) & 1) * 128 + (wid * 2 + _l) * 8;                                    \
        const ushort* _g = ah + (size_t)(_rb + _r0 + (lane >> 3)) * DIM                    \
                           + (kt) * 64 + (((lane & 7) ^ (lane >> 3)) * 8);                 \
        __builtin_amdgcn_global_load_lds(                                                  \
            (const __attribute__((address_space(1))) uint*)_g,                             \
            (__attribute__((address_space(3))) uint*)(&lds[buf][_arr][0][0] + (size_t)_r0 * 64), \
            16, 0, 0);                                                                     \
    }                                                                                      \
} while (0)

// swizzled fragment read: logical chunk c = ks*4 + fkk, physical = c ^ (fr&7)
#define RD(arr, lrow, ks) \
    (*reinterpret_cast<const short8*>(&lds[cur][arr][0][0] + (size_t)(lrow) * 64 + \
        (((ks) * 4 + fkk) ^ (fr & 7)) * 8))

__global__ __launch_bounds__(512, 2) void gemm_kernel(char* __restrict__ wsb,
                                                      float* __restrict__ out) {
    const ushort* ah = (const ushort*)(wsb + AH_OFF);
    const float*  sq = (const float*)(wsb + SQ_OFF);
    uint*  ght = (uint*)(wsb + GHT_OFF);
    uint*  ghn = (uint*)(wsb + GHN_OFF);
    uint*  cnt = (uint*)(wsb + CNT_OFF);

    // 128 KiB: 2 dbuf x {A[256][64], B[256][64]} bf16; first 32 KB reused as hist
    __shared__ __align__(16) ushort lds[2][2][256][64];
    __shared__ uint lowcnt;
    __shared__ float fred[8];

    // XCD swizzle (136 = 8*17, bijective) then triangular decode
    int b = (int)blockIdx.x;
    b = (b & 7) * 17 + (b >> 3);
    int bi = (int)((sqrtf(8.0f * (float)b + 1.0f) - 1.0f) * 0.5f);
    while ((bi + 1) * (bi + 2) / 2 <= b) ++bi;
    while (bi * (bi + 1) / 2 > b) --bi;
    int bj = b - bi * (bi + 1) / 2;          // bj <= bi

    int t = threadIdx.x;
    int lane = t & 63, wid = t >> 6;         // 8 waves
    int wm = wid >> 2, wn = wid & 3;         // 2x4 wave grid: 128 rows x 64 cols per wave
    int rowbase = bi * 256, colbase = bj * 256;

    f32x4 acc[8][4] = {};
    int fr = lane & 15, fkk = lane >> 4;

    // prologue: stage all 4 units of k-tile 0 into buffer 0
    STAGEU(0, 0, 0); STAGEU(0, 1, 0); STAGEU(0, 2, 0); STAGEU(0, 3, 0);

    short8 fa[4][2], fb[4][2];

    for (int kt = 0; kt < 16; ++kt) {
        int cur = kt & 1, nxt = cur ^ 1;
        bool st = kt < 15;
        // ======== P1: quadrant (mh0, nh0) ========
        if (st) {
            STAGEU(nxt, 0, kt + 1);
            asm volatile("s_waitcnt vmcnt(2)" ::: "memory");   // all of tile kt landed
        } else {
            asm volatile("s_waitcnt vmcnt(0)" ::: "memory");
        }
        __builtin_amdgcn_s_barrier();
#pragma unroll
        for (int mi = 0; mi < 4; ++mi)
#pragma unroll
            for (int ks = 0; ks < 2; ++ks)
                fa[mi][ks] = RD(0, wm * 128 + mi * 16 + fr, ks);
#pragma unroll
        for (int ni = 0; ni < 2; ++ni)
#pragma unroll
            for (int ks = 0; ks < 2; ++ks)
                fb[ni][ks] = RD(1, wn * 64 + ni * 16 + fr, ks);
        __builtin_amdgcn_s_setprio(1);
#pragma unroll
        for (int mi = 0; mi < 4; ++mi)
#pragma unroll
            for (int ni = 0; ni < 2; ++ni)
#pragma unroll
                for (int ks = 0; ks < 2; ++ks)
                    acc[mi][ni] = __builtin_amdgcn_mfma_f32_16x16x32_bf16(fa[mi][ks], fb[ni][ks], acc[mi][ni], 0, 0, 0);
        __builtin_amdgcn_s_setprio(0);
        __builtin_amdgcn_s_barrier();
        // ======== P2: quadrant (mh0, nh1) ========
        if (st) STAGEU(nxt, 1, kt + 1);
        __builtin_amdgcn_s_barrier();
#pragma unroll
        for (int ni = 0; ni < 2; ++ni)
#pragma unroll
            for (int ks = 0; ks < 2; ++ks)
                fb[2 + ni][ks] = RD(1, wn * 64 + 32 + ni * 16 + fr, ks);
        __builtin_amdgcn_s_setprio(1);
#pragma unroll
        for (int mi = 0; mi < 4; ++mi)
#pragma unroll
            for (int ni = 0; ni < 2; ++ni)
#pragma unroll
                for (int ks = 0; ks < 2; ++ks)
                    acc[mi][2 + ni] = __builtin_amdgcn_mfma_f32_16x16x32_bf16(fa[mi][ks], fb[2 + ni][ks], acc[mi][2 + ni], 0, 0, 0);
        __builtin_amdgcn_s_setprio(0);
        __builtin_amdgcn_s_barrier();
        // ======== P3: quadrant (mh1, nh1) ========
        if (st) STAGEU(nxt, 2, kt + 1);
        __builtin_amdgcn_s_barrier();
#pragma unroll
        for (int mi = 0; mi < 4; ++mi)
#pragma unroll
            for (int ks = 0; ks < 2; ++ks)
                fa[mi][ks] = RD(0, wm * 128 + 64 + mi * 16 + fr, ks);
        __builtin_amdgcn_s_setprio(1);
#pragma unroll
        for (int mi = 0; mi < 4; ++mi)
#pragma unroll
            for (int ni = 0; ni < 2; ++ni)
#pragma unroll
                for (int ks = 0; ks < 2; ++ks)
                    acc[4 + mi][2 + ni] = __builtin_amdgcn_mfma_f32_16x16x32_bf16(fa[mi][ks], fb[2 + ni][ks], acc[4 + mi][2 + ni], 0, 0, 0);
        __builtin_amdgcn_s_setprio(0);
        __builtin_amdgcn_s_barrier();
        // ======== P4: quadrant (mh1, nh0) ========
        if (st) STAGEU(nxt, 3, kt + 1);
        __builtin_amdgcn_s_barrier();
        __builtin_amdgcn_s_setprio(1);
#pragma unroll
        for (int mi = 0; mi < 4; ++mi)
#pragma unroll
            for (int ni = 0; ni < 2; ++ni)
#pragma unroll
                for (int ks = 0; ks < 2; ++ks)
                    acc[4 + mi][ni] = __builtin_amdgcn_mfma_f32_16x16x32_bf16(fa[mi][ks], fb[ni][ks], acc[4 + mi][ni], 0, 0, 0);
        __builtin_amdgcn_s_setprio(0);
        __builtin_amdgcn_s_barrier();
    }
    __syncthreads();

    // ---- hist: bit30-split from registers (sign is BLOCK-uniform)
    uint* h = (uint*)&lds[0][0][0][0];        // 8192 packed words = 32 KB
    for (int i = t; i < 8192; i += 512) h[i] = 0;
    if (t == 0) lowcnt = 0;
    __syncthreads();

    uint w = (bi == bj) ? 1u : 2u;
    int fq = fkk;
#pragma unroll
    for (int mi = 0; mi < 8; ++mi) {
#pragma unroll
        for (int ni = 0; ni < 4; ++ni) {
            int gj = colbase + wn * 64 + ni * 16 + fr;
            float sqj = sq[gj];
#pragma unroll
            for (int r = 0; r < 4; ++r) {
                int gi = rowbase + wm * 128 + mi * 16 + fq * 4 + r;
                float v = fmaxf(sq[gi] + sqj - 2.0f * acc[mi][ni][r], 0.0f);
                uint bits = __float_as_uint(v);
                if (bits & 0x40000000u) {
                    uint k14 = (bits >> 16) & 0x3FFFu;
                    atomicAdd(&h[k14 >> 1], (k14 & 1) ? (w << 16) : w);
                } else {
                    atomicAdd(&lowcnt, w);             // rare (diag zeros + tiny tail)
                }
            }
        }
    }
    __syncthreads();

    // ---- flush. Always -> total; cross-half blocks also -> neg hist.
    bool crosshalf = (bi < 8) != (bj < 8);
    for (int i = t; i < 8192; i += 512) {
        uint wd = h[i];
        if (wd) {
            uint lo = wd & 0xFFFFu, hi2 = wd >> 16;
            if (lo)  { atomicAdd(&ght[2 * i],     lo);  if (crosshalf) atomicAdd(&ghn[2 * i],     lo); }
            if (hi2) { atomicAdd(&ght[2 * i + 1], hi2); if (crosshalf) atomicAdd(&ghn[2 * i + 1], hi2); }
        }
    }
    if (t == 0 && lowcnt) {
        atomicAdd(&ght[16384], lowcnt);
        if (crosshalf) atomicAdd(&ghn[16384], lowcnt);
    }

    // ---- last-flusher: median AND loss from the histograms
    __syncthreads();
    if (t == 0) {
        __threadfence();
        h[0] = (atomicAdd(&cnt[0], 1u) == gridDim.x - 1) ? 1u : 0u;
    }
    __syncthreads();
    bool last = h[0] != 0;
    __syncthreads();
    if (!last) return;

    uint* part = h + 16;       // 512
    uint* loc  = h + 544;      // 2
    uint* lin  = h + 560;      // 32
    uint s = 0;
    for (int i = 0; i < 32; ++i) s += AGLOAD(&ght[t * 32 + i]);   // 512 thr x 32 bins
    part[t] = s;
    __syncthreads();
    if (t == 0) {
        uint k = KMED - AGLOAD(&ght[16384]);   // below-2.0 values rank below everything
        uint cum = 0; int seg = 0;
        for (; seg < 512; ++seg) { uint c = part[seg]; if (cum + c > k) break; cum += c; }
        loc[0] = (uint)seg; loc[1] = k - cum;
    }
    __syncthreads();
    int seg = (int)loc[0];
    if (t < 32) lin[t] = AGLOAD(&ght[seg * 32 + t]);
    __syncthreads();
    if (t == 0) {
        uint k = loc[1], cum = 0; int bb = 0;
        for (; bb < 32; ++bb) { uint c = lin[bb]; if (cum + c > k) break; cum += c; }
        // median resolved to bits >= 16; bin midpoint (err <= 8 abs @ ~2048)
        uint mbits = 0x40000000u | ((uint)(seg * 32 + bb) << 16) | 0x8000u;
        float median = __uint_as_float(mbits);
        float logn = logf(2048.0f + 1e-8f);
        float bw = sqrtf(0.5f * median / logn);
        out[1] = bw;                               // bandwidth
        ((float*)loc)[1] = logn / median;          // itb -> LDS for all threads
    }
    __syncthreads();
    float itb = ((float*)loc)[1];

    // loss = sum over bins of (total - 2*neg) * exp(-mid * itb), + low-count at exp(0)=1
    float local = 0.0f;
    for (int i = 0; i < 32; ++i) {
        int bidx = t * 32 + i;
        int tot = (int)AGLOAD(&ght[bidx]);
        int neg = (int)AGLOAD(&ghn[bidx]);
        int sgn = tot - 2 * neg;
        if (sgn) {
            float mid = __uint_as_float(0x40000000u | ((uint)bidx << 16) | 0x8000u);
            local += (float)sgn * __expf(-mid * itb);
        }
    }
    if (t == 0)
        local += (float)((int)AGLOAD(&ght[16384]) - 2 * (int)AGLOAD(&ghn[16384]));  // exp(0)=1
    for (int o = 32; o; o >>= 1) local += __shfl_down(local, o);
    if ((t & 63) == 0) fred[t >> 6] = local;
    __syncthreads();
    if (t == 0) {
        float bs = fred[0] + fred[1] + fred[2] + fred[3]
                 + fred[4] + fred[5] + fred[6] + fred[7];
        out[0] = bs / 4194304.0f;              // mean over N*N, N=2048
    }
}

// ---------------------------------------------------------------- launch (2 dispatches)
extern "C" void kernel_launch(void* const* d_in, const int* in_sizes, int n_in,
                              void* d_out, int out_size, void* d_ws, size_t ws_size,
                              hipStream_t stream) {
    const float* src = (const float*)d_in[0];
    const float* tgt = (const float*)d_in[1];
    float* out = (float*)d_out;
    char* ws = (char*)d_ws;

    convert_kernel<<<MROWS, 256, 0, stream>>>(src, tgt, ws);
    gemm_kernel<<<NTRI, 512, 0, stream>>>(ws, out);
}